// Round 10
// baseline (313.565 us; speedup 1.0000x reference)
//
#include <hip/hip_runtime.h>

// GCN 2-layer forward. f32 wire; bf16 MFMA GEMMs (f32 acc); bf16 gather tables;
// padded-ELL adjacency. Non-temporal edge-stream loads in the fill (keeps L2
// free for dirty ELL lines -> ~1 write-back per line instead of ~16).

#define DIN 128
#define DHID 128
#define DOUT 64
#define ELLW 64     // max in-degree (Poisson(16): P(>=64) ~ 1e-22)
#define GPART 8
#define BPG 256

typedef __attribute__((ext_vector_type(4))) float f32x4;
typedef __attribute__((ext_vector_type(8))) short bf16x8;
typedef __attribute__((ext_vector_type(4))) int i32x4;

__device__ __forceinline__ float bf2f(unsigned int u16) {
    return __uint_as_float(u16 << 16);
}
__device__ __forceinline__ unsigned short f2bf(float f) {
    unsigned int u = __float_as_uint(f);
    u += 0x7fffu + ((u >> 16) & 1u);   // RNE
    return (unsigned short)(u >> 16);
}
__device__ __forceinline__ unsigned int pack2(float a, float b) {
    return (unsigned int)f2bf(a) | ((unsigned int)f2bf(b) << 16);
}

// ---------------- pack W1/W2 into MFMA B-fragment order, bf16 ----------------
__global__ __launch_bounds__(256) void k_packW(const float* __restrict__ W1,
                                               const float* __restrict__ W2,
                                               unsigned short* __restrict__ w1p,
                                               unsigned short* __restrict__ w2p) {
    int id = blockIdx.x * 256 + threadIdx.x;
    if (id < 2048) {                     // W1: 8 n-tiles x 4 k-steps x 64 lanes
        int lane = id & 63, s = (id >> 6) & 3, t = id >> 8;
        int n = t * 16 + (lane & 15);
        int k0 = s * 32 + (lane >> 4) * 8;
#pragma unroll
        for (int j = 0; j < 8; ++j)
            w1p[(size_t)id * 8 + j] = f2bf(W1[(k0 + j) * DHID + n]);
    } else if (id < 3072) {              // W2: 4 n-tiles x 4 k-steps x 64 lanes
        int id2 = id - 2048;
        int lane = id2 & 63, s = (id2 >> 6) & 3, t = id2 >> 8;
        int n = t * 16 + (lane & 15);
        int k0 = s * 32 + (lane >> 4) * 8;
#pragma unroll
        for (int j = 0; j < 8; ++j)
            w2p[(size_t)id2 * 8 + j] = f2bf(W2[(k0 + j) * DOUT + n]);
    }
}

// ---------------- fused: ELL fill (blocks < FB) + GEMM1 (blocks >= FB) ----------------
__device__ __forceinline__ void fill_edge(int c, int r, int lo, int hi,
                                          int* __restrict__ deg, int* __restrict__ ell) {
    if (c >= lo && c < hi) {
        int k = atomicAdd(&deg[c], 1);
        if (k < ELLW) ell[(size_t)c * ELLW + k] = r;
    }
}

__global__ __launch_bounds__(256) void k_fill_gemm1(
        const int* __restrict__ rows, const int* __restrict__ cols,
        int* __restrict__ deg, int* __restrict__ ell,
        int E, int perBlock, int R, int FB,
        const float* __restrict__ x, const unsigned short* __restrict__ w1p,
        unsigned short* __restrict__ h1b, int N) {
    if ((int)blockIdx.x < FB) {
        // ----- ELL fill, dst-range partitioned, non-temporal int4 edge scan -----
        int g  = blockIdx.x & (GPART - 1);
        int cb = blockIdx.x >> 3;
        int lo = g * R, hi = lo + R;
        int eBeg = cb * perBlock;
        int eEnd = eBeg + perBlock; if (eEnd > E) eEnd = E;
        for (int e = eBeg + 4 * threadIdx.x; e < eEnd; e += 4 * 256) {
            if (e + 3 < eEnd) {
                i32x4 c4 = __builtin_nontemporal_load((const i32x4*)(cols + e));
                i32x4 r4 = __builtin_nontemporal_load((const i32x4*)(rows + e));
                fill_edge(c4.x, r4.x, lo, hi, deg, ell);
                fill_edge(c4.y, r4.y, lo, hi, deg, ell);
                fill_edge(c4.z, r4.z, lo, hi, deg, ell);
                fill_edge(c4.w, r4.w, lo, hi, deg, ell);
            } else {
                for (int j = e; j < eEnd; ++j) fill_edge(cols[j], rows[j], lo, hi, deg, ell);
            }
        }
        return;
    }
    // ----- GEMM1 (MFMA): h1b[N,128] bf16 = bf16(x) @ w1p -----
    int bid = blockIdx.x - FB;
    int wave = threadIdx.x >> 6, lane = threadIdx.x & 63;
    int quad = lane >> 4, qr = lane & 15;
    int rowBase = bid * 64 + wave * 16;
    int arow = rowBase + qr;
    bool rowOK = arow < N;
    f32x4 acc[8] = {};
#pragma unroll
    for (int s = 0; s < 4; ++s) {
        bf16x8 a = {};
        if (rowOK) {
            const float* ap = x + (size_t)arow * DIN + s * 32 + quad * 8;
            float4 lo = *(const float4*)ap;
            float4 hi = *(const float4*)(ap + 4);
            a[0] = (short)f2bf(lo.x); a[1] = (short)f2bf(lo.y);
            a[2] = (short)f2bf(lo.z); a[3] = (short)f2bf(lo.w);
            a[4] = (short)f2bf(hi.x); a[5] = (short)f2bf(hi.y);
            a[6] = (short)f2bf(hi.z); a[7] = (short)f2bf(hi.w);
        }
#pragma unroll
        for (int t = 0; t < 8; ++t) {
            bf16x8 b = *(const bf16x8*)(w1p + ((size_t)(t * 4 + s) * 64 + lane) * 8);
            acc[t] = __builtin_amdgcn_mfma_f32_16x16x32_bf16(a, b, acc[t], 0, 0, 0);
        }
    }
#pragma unroll
    for (int t = 0; t < 8; ++t)
#pragma unroll
        for (int i = 0; i < 4; ++i) {
            int r = rowBase + quad * 4 + i;
            if (r < N) h1b[(size_t)r * DHID + t * 16 + qr] = f2bf(acc[t][i]);
        }
}

// ---------------- gather layer 1 + fused bias/self-loop/relu -> bf16 hact ----------------
__global__ __launch_bounds__(256) void k_gather1(const int* __restrict__ deg,
                                                 const int* __restrict__ ell,
                                                 const unsigned int* __restrict__ h1u,
                                                 const float* __restrict__ b1,
                                                 unsigned int* __restrict__ hactu, int N) {
    int w = (blockIdx.x * 256 + threadIdx.x) >> 6;
    int lane = threadIdx.x & 63;
    if (w >= N) return;
    int dfull = deg[w];
    int d = dfull > ELLW ? ELLW : dfull;
    int iv = ell[(size_t)w * ELLW + lane];                      // 256B coalesced
    float dv = (lane < d) ? rsqrtf((float)(deg[iv] + 1)) : 0.f; // per-lane weight
    float a0 = 0.f, a1 = 0.f;
    int e = 0;
    for (; e + 8 <= d; e += 8) {
        int s[8]; float wg[8]; unsigned int v[8];
#pragma unroll
        for (int j = 0; j < 8; ++j) { s[j] = __shfl(iv, e + j); wg[j] = __shfl(dv, e + j); }
#pragma unroll
        for (int j = 0; j < 8; ++j) v[j] = h1u[(size_t)s[j] * 64 + lane];
#pragma unroll
        for (int j = 0; j < 8; ++j) {
            a0 = fmaf(wg[j], bf2f(v[j] & 0xffffu), a0);
            a1 = fmaf(wg[j], bf2f(v[j] >> 16), a1);
        }
    }
    for (; e + 4 <= d; e += 4) {
        int s[4]; float wg[4]; unsigned int v[4];
#pragma unroll
        for (int j = 0; j < 4; ++j) { s[j] = __shfl(iv, e + j); wg[j] = __shfl(dv, e + j); }
#pragma unroll
        for (int j = 0; j < 4; ++j) v[j] = h1u[(size_t)s[j] * 64 + lane];
#pragma unroll
        for (int j = 0; j < 4; ++j) {
            a0 = fmaf(wg[j], bf2f(v[j] & 0xffffu), a0);
            a1 = fmaf(wg[j], bf2f(v[j] >> 16), a1);
        }
    }
    for (; e < d; ++e) {
        int s0 = __shfl(iv, e);
        float w0 = __shfl(dv, e);
        unsigned int v0 = h1u[(size_t)s0 * 64 + lane];
        a0 = fmaf(w0, bf2f(v0 & 0xffffu), a0); a1 = fmaf(w0, bf2f(v0 >> 16), a1);
    }
    float di = rsqrtf((float)(dfull + 1)), self = di * di;
    unsigned int hv = h1u[(size_t)w * 64 + lane];
    float2 bv = *(const float2*)(b1 + 2 * lane);
    float r0 = fmaf(di, a0, fmaf(self, bf2f(hv & 0xffffu), bv.x));
    float r1 = fmaf(di, a1, fmaf(self, bf2f(hv >> 16), bv.y));
    hactu[(size_t)w * 64 + lane] = pack2(fmaxf(r0, 0.f), fmaxf(r1, 0.f));
}

// ---------------- GEMM2 (MFMA): h2b[N,64] bf16 = hact(bf16) @ w2p ----------------
__global__ __launch_bounds__(256) void k_gemm2(const unsigned short* __restrict__ hactb,
                                               const unsigned short* __restrict__ w2p,
                                               unsigned short* __restrict__ h2b, int N) {
    int wave = threadIdx.x >> 6, lane = threadIdx.x & 63;
    int quad = lane >> 4, qr = lane & 15;
    int rowBase = blockIdx.x * 64 + wave * 16;
    int arow = rowBase + qr;
    bool rowOK = arow < N;
    f32x4 acc[4] = {};
#pragma unroll
    for (int s = 0; s < 4; ++s) {
        bf16x8 a = {};
        if (rowOK) a = *(const bf16x8*)(hactb + (size_t)arow * DHID + s * 32 + quad * 8);
#pragma unroll
        for (int t = 0; t < 4; ++t) {
            bf16x8 b = *(const bf16x8*)(w2p + ((size_t)(t * 4 + s) * 64 + lane) * 8);
            acc[t] = __builtin_amdgcn_mfma_f32_16x16x32_bf16(a, b, acc[t], 0, 0, 0);
        }
    }
#pragma unroll
    for (int t = 0; t < 4; ++t)
#pragma unroll
        for (int i = 0; i < 4; ++i) {
            int r = rowBase + quad * 4 + i;
            if (r < N) h2b[(size_t)r * DOUT + t * 16 + qr] = f2bf(acc[t][i]);
        }
}

// ---------------- gather layer 2 + fused bias/self-loop; writes d_out (f32) ----------------
__global__ __launch_bounds__(256) void k_gather2(const int* __restrict__ deg,
                                                 const int* __restrict__ ell,
                                                 const unsigned short* __restrict__ h2u,
                                                 const float* __restrict__ b2,
                                                 float* __restrict__ out, int N) {
    int w = (blockIdx.x * 256 + threadIdx.x) >> 6;
    int lane = threadIdx.x & 63;
    if (w >= N) return;
    int dfull = deg[w];
    int d = dfull > ELLW ? ELLW : dfull;
    int iv = ell[(size_t)w * ELLW + lane];
    float dv = (lane < d) ? rsqrtf((float)(deg[iv] + 1)) : 0.f;
    float a = 0.f;
    int e = 0;
    for (; e + 8 <= d; e += 8) {
        int s[8]; float wg[8]; float v[8];
#pragma unroll
        for (int j = 0; j < 8; ++j) { s[j] = __shfl(iv, e + j); wg[j] = __shfl(dv, e + j); }
#pragma unroll
        for (int j = 0; j < 8; ++j) v[j] = bf2f((unsigned int)h2u[(size_t)s[j] * DOUT + lane]);
#pragma unroll
        for (int j = 0; j < 8; ++j) a = fmaf(wg[j], v[j], a);
    }
    for (; e + 4 <= d; e += 4) {
        int s[4]; float wg[4]; float v[4];
#pragma unroll
        for (int j = 0; j < 4; ++j) { s[j] = __shfl(iv, e + j); wg[j] = __shfl(dv, e + j); }
#pragma unroll
        for (int j = 0; j < 4; ++j) v[j] = bf2f((unsigned int)h2u[(size_t)s[j] * DOUT + lane]);
#pragma unroll
        for (int j = 0; j < 4; ++j) a = fmaf(wg[j], v[j], a);
    }
    for (; e < d; ++e) {
        int s0 = __shfl(iv, e);
        float w0 = __shfl(dv, e);
        a = fmaf(w0, bf2f((unsigned int)h2u[(size_t)s0 * DOUT + lane]), a);
    }
    float di = rsqrtf((float)(dfull + 1)), self = di * di;
    float hv = bf2f((unsigned int)h2u[(size_t)w * DOUT + lane]);
    out[(size_t)w * DOUT + lane] = fmaf(di, a, fmaf(self, hv, b2[lane]));
}

extern "C" void kernel_launch(void* const* d_in, const int* in_sizes, int n_in,
                              void* d_out, int out_size, void* d_ws, size_t ws_size,
                              hipStream_t stream) {
    const float* x  = (const float*)d_in[0];
    const int*   ei = (const int*)d_in[1];
    const float* W1 = (const float*)d_in[2];
    const float* b1 = (const float*)d_in[3];
    const float* W2 = (const float*)d_in[4];
    const float* b2 = (const float*)d_in[5];

    const int N = in_sizes[0] / DIN;     // 100000
    const int E = in_sizes[1] / 2;       // 1600000
    const int* rows = ei;                // sources
    const int* cols = ei + E;            // destinations

    // workspace (~77.5 MB)
    char* p = (char*)d_ws;
    int*   ell  = (int*)p;                    p += (size_t)N * ELLW * 4;   // 25.6 MB
    unsigned short* h1b = (unsigned short*)p;   p += (size_t)N * DHID * 2; // 25.6 MB
    unsigned short* hactb = (unsigned short*)p; p += (size_t)N * DHID * 2; // 25.6 MB
    unsigned short* w1p = (unsigned short*)p;   p += (size_t)2048 * 8 * 2; // 32 KB
    unsigned short* w2p = (unsigned short*)p;   p += (size_t)1024 * 8 * 2; // 16 KB
    int*   deg  = (int*)p;                    p += (size_t)N * 4;
    unsigned short* h2b = h1b;   // alias: h1 dead after k_gather1

    const int R = (N + GPART - 1) / GPART;
    int perBlock = (E + BPG - 1) / BPG;
    perBlock = (perBlock + 3) & ~3;                  // int4-aligned chunks
    const int FB = GPART * BPG;                      // 2048 fill blocks
    const int GB = (N + 63) / 64;                    // 1563 gemm blocks

    k_packW<<<12, 256, 0, stream>>>(W1, W2, w1p, w2p);
    (void)hipMemsetAsync(deg, 0, (size_t)N * 4, stream);

    // fill + gemm1 fused (independent work, concurrent blocks)
    k_fill_gemm1<<<FB + GB, 256, 0, stream>>>(rows, cols, deg, ell, E, perBlock, R, FB,
                                              x, w1p, h1b, N);

    // layer 1 aggregate
    k_gather1<<<(N + 3) / 4, 256, 0, stream>>>(deg, ell, (const unsigned int*)h1b,
                                               b1, (unsigned int*)hactb, N);

    // layer 2
    k_gemm2<<<(N + 63) / 64, 256, 0, stream>>>(hactb, w2p, h2b, N);
    k_gather2<<<(N + 3) / 4, 256, 0, stream>>>(deg, ell, h2b, b2, (float*)d_out, N);
}